// Round 17
// baseline (148.465 us; speedup 1.0000x reference)
//
#include <hip/hip_runtime.h>

// ---------------- problem constants ----------------
#define BATCH 2
#define SEQ 2048
#define DMODEL 2048
#define NHEADS 16
#define NKV 4
#define DK 128
#define WINH 64   // WINDOW/2
#define NQKV 3072 // 2048 q + 512 k + 512 v

typedef unsigned short ushort_t;
typedef __attribute__((ext_vector_type(8))) __bf16 bf16x8;
typedef __attribute__((ext_vector_type(4))) float f32x4;

__device__ __forceinline__ float b2f(ushort_t u) {
    union { unsigned int i; float f; } v; v.i = ((unsigned int)u) << 16; return v.f;
}
__device__ __forceinline__ ushort_t f2b(float f) {
    union { float f; unsigned int i; } v; v.f = f;
    unsigned int r = v.i + 0x7FFFu + ((v.i >> 16) & 1u);
    return (ushort_t)(r >> 16);
}

// async global->LDS, 16B/lane; LDS dest wave-uniform base + lane*16.
__device__ __forceinline__ void gload_lds16(const ushort_t* g, ushort_t* l) {
    __builtin_amdgcn_global_load_lds(
        (__attribute__((address_space(1))) void*)(void*)const_cast<ushort_t*>(g),
        (__attribute__((address_space(3))) void*)l, 16, 0, 0);
}

// ---------------------------------------------------------------
// prep: all input conversion in ONE launch (blockIdx ranges).
// ~111 MB moved -> ~17us, at HBM roofline.
// ---------------------------------------------------------------
__global__ __launch_bounds__(256) void prep(
    const float* __restrict__ x,  const float* __restrict__ Wq,
    const float* __restrict__ Wk, const float* __restrict__ Wv,
    const float* __restrict__ Wo, const float* __restrict__ bq,
    const float* __restrict__ bk, const float* __restrict__ bv,
    ushort_t* __restrict__ xb, ushort_t* __restrict__ wdst,
    float* __restrict__ bqkv, float2* __restrict__ rtab)
{
    const int blk = blockIdx.x;
    const int tid = threadIdx.x;
    if (blk < 4096) {                               // x cast
        int i = blk * 256 + tid;
        float4 a = *((const float4*)x + i * 2);
        float4 b = *((const float4*)x + i * 2 + 1);
        ushort_t o[8] = { f2b(a.x), f2b(a.y), f2b(a.z), f2b(a.w),
                          f2b(b.x), f2b(b.y), f2b(b.z), f2b(b.w) };
        *((uint4*)xb + i) = *(const uint4*)o;
    } else if (blk < 9216) {                        // weights cast
        int i = (blk - 4096) * 256 + tid;
        int row = i >> 8, c8 = i & 255;
        const float* src;
        if      (row < 2048) src = Wq + (size_t)row * 2048;
        else if (row < 2560) src = Wk + (size_t)(row - 2048) * 2048;
        else if (row < 3072) src = Wv + (size_t)(row - 2560) * 2048;
        else                 src = Wo + (size_t)(row - 3072) * 2048;
        float4 a = *((const float4*)src + c8 * 2);
        float4 b = *((const float4*)src + c8 * 2 + 1);
        ushort_t o[8] = { f2b(a.x), f2b(a.y), f2b(a.z), f2b(a.w),
                          f2b(b.x), f2b(b.y), f2b(b.z), f2b(b.w) };
        *((uint4*)wdst + i) = *(const uint4*)o;
    } else if (blk < 9228) {                        // bias concat
        int i = (blk - 9216) * 256 + tid;
        if (i < 2048) bqkv[i] = bq[i];
        else if (i < 2560) bqkv[i] = bk[i - 2048];
        else if (i < 3072) bqkv[i] = bv[i - 2560];
    } else {                                        // rope table
        int i = (blk - 9228) * 256 + tid;           // 0..131071
        int s = i >> 6, dd = i & 63;
        float invfreq = exp2f(-(float)(2 * dd) * (13.287712379549449f / 128.0f));
        float ang = (float)s * invfreq;
        rtab[i] = make_float2(cosf(ang), sinf(ang));
    }
}

// ---------------------------------------------------------------
// QKV GEMM — 8-phase counted-vmcnt schedule (m201 template, plain HIP).
// BM=BN=256, BK=64, 512 thr = 8 waves (2M x 4N), per-wave 128x64 out
// (acc[8][4]). LDS = 8 half-slots x 16KB = 128KB (2 K-tiles deep).
// Half h of tile t=h>>2: j=h&3 in {A-k0, B-k0, A-k1, B-k1}; slot h&7.
// Phase q of tile t: kk=q>>1 (K-half), mh=q&1 (m-half): 8 ds_read_b128
// + 16 MFMA. Each phase stages half p+6 (p=4t+q): 6-half prefetch depth.
// vmcnt LEDGER (2 vm-ops/half): wait vmcnt(8) at q=0,2 -> needed halves
// landed exactly; tail tile: vmcnt(4)/vmcnt(0). Overwrite safety: phase
// p's DMA targets slot of half p-2, fully read >=1 trailing barrier ago
// (pre-barrier lgkmcnt(0) guards cross-wave); staged slot never collides
// with current phase's read slots (verified for all q).
// Swizzle: 32-k half, 4 slots; chunk(r,s) holds src k-slot s^((r>>1)&3)
// (R4/R5-verified, 0 bank conflicts). XCD swizzle (grid 192 % 8 == 0).
// ---------------------------------------------------------------
__global__ __launch_bounds__(512) void gemm_qkv_8p(
    const ushort_t* __restrict__ A, const ushort_t* __restrict__ W,
    const float* __restrict__ bias, ushort_t* __restrict__ C,
    int M, int N, int K)
{
    extern __shared__ __attribute__((aligned(16))) ushort_t smem[]; // 8 x 8192 elems

    const int tid  = threadIdx.x;
    const int lane = tid & 63;
    const int wave = tid >> 6;      // 0..7
    const int wm   = wave >> 2;     // 0..1 -> rows wm*128
    const int wn   = wave & 3;      // 0..3 -> cols wn*64
    const int nbn  = N >> 8;        // 12

    int nwg = gridDim.x;
    int bid = blockIdx.x;
    int nb  = (nwg & 7) ? bid : ((bid & 7) * (nwg >> 3) + (bid >> 3));
    const int bm = nb / nbn;
    const int bn = nb % nbn;
    const int m0 = bm << 8, n0 = bn << 8;

    f32x4 acc[8][4] = {};

    const int frow = lane & 15;
    const int kg   = lane >> 4;

    // staging geometry: half = 256 rows x 32 k = 1024 chunks of 16B;
    // thread does chunks {tid, 512+tid}. chunk c: r=c>>2, lin slot c&3,
    // src k-slot (c&3)^((r>>1)&3). LDS dest linear.
    const ushort_t* aP[2]; const ushort_t* bP[2]; int lofs[2];
#pragma unroll
    for (int rd = 0; rd < 2; ++rd) {
        int c = rd * 512 + tid;
        int r = c >> 2, s = c & 3;
        int ks = s ^ ((r >> 1) & 3);
        aP[rd] = A + (size_t)(m0 + r) * K + ks * 8;
        bP[rd] = W + (size_t)(n0 + r) * K + ks * 8;
        lofs[rd] = (rd * 512 + wave * 64) * 8;      // wave-uniform elem base
    }

    const int nt = K >> 6;          // 32 K-tiles
    const int H  = nt << 2;         // 128 halves

    auto stage = [&](int h) {
        int ts = h >> 2, j = h & 3;
        int kofs = (ts << 6) + ((j >> 1) << 5);     // t*64 + khalf*32
        ushort_t* dst = smem + (h & 7) * 8192;
        if ((j & 1) == 0) {
            gload_lds16(aP[0] + kofs, dst + lofs[0]);
            gload_lds16(aP[1] + kofs, dst + lofs[1]);
        } else {
            gload_lds16(bP[0] + kofs, dst + lofs[0]);
            gload_lds16(bP[1] + kofs, dst + lofs[1]);
        }
    };

    // prologue: stage halves 0..5 (tile 0 complete + half of tile 1)
#pragma unroll
    for (int h = 0; h < 6; ++h) stage(h);

    for (int t = 0; t < nt; ++t) {
#pragma unroll
        for (int q = 0; q < 4; ++q) {
            const int p = (t << 2) + q;
            if (p + 6 < H) stage(p + 6);
            if (q == 0) {
                if (t == nt - 1) asm volatile("s_waitcnt vmcnt(4)" ::: "memory");
                else             asm volatile("s_waitcnt vmcnt(8)" ::: "memory");
            } else if (q == 2) {
                if (t == nt - 1) asm volatile("s_waitcnt vmcnt(0)" ::: "memory");
                else             asm volatile("s_waitcnt vmcnt(8)" ::: "memory");
            }
            __builtin_amdgcn_s_barrier();           // halves confirmed block-wide
            asm volatile("" ::: "memory");          // keep LDS reads below
            __builtin_amdgcn_sched_barrier(0);

            const int kk = q >> 1, mh = q & 1;
            const ushort_t* As = smem + (((t << 2) + (kk << 1)) & 7) * 8192;
            const ushort_t* Bs = smem + (((t << 2) + (kk << 1) + 1) & 7) * 8192;
            bf16x8 af[4], bf[4];
#pragma unroll
            for (int mf = 0; mf < 4; ++mf) {
                int r = (wm << 7) + ((mh << 2) + mf) * 16 + frow;
                af[mf] = *(const bf16x8*)(As + (r * 4 + (kg ^ ((r >> 1) & 3))) * 8);
            }
#pragma unroll
            for (int nf = 0; nf < 4; ++nf) {
                int r = (wn << 6) + nf * 16 + frow;
                bf[nf] = *(const bf16x8*)(Bs + (r * 4 + (kg ^ ((r >> 1) & 3))) * 8);
            }
            __builtin_amdgcn_s_setprio(1);
#pragma unroll
            for (int mf = 0; mf < 4; ++mf)
#pragma unroll
                for (int nf = 0; nf < 4; ++nf)
                    acc[(mh << 2) + mf][nf] = __builtin_amdgcn_mfma_f32_16x16x32_bf16(
                        af[mf], bf[nf], acc[(mh << 2) + mf][nf], 0, 0, 0);
            __builtin_amdgcn_s_setprio(0);
            asm volatile("s_waitcnt lgkmcnt(0)" ::: "memory"); // reads retired
            __builtin_amdgcn_s_barrier();           // next phase's DMA safe
            __builtin_amdgcn_sched_barrier(0);
        }
    }

    // D: col = lane&15, row = (lane>>4)*4 + reg  [m89-verified]
    const int orow = (lane >> 4) << 2;
    const int ocol = lane & 15;
#pragma unroll
    for (int nf = 0; nf < 4; ++nf) {
        int col = n0 + (wn << 6) + nf * 16 + ocol;
        float bvf = bias[col];
#pragma unroll
        for (int mf = 0; mf < 8; ++mf) {
#pragma unroll
            for (int r = 0; r < 4; ++r) {
                int row = m0 + (wm << 7) + mf * 16 + orow + r;
                C[(size_t)row * N + col] = f2b(acc[mf][nf][r] + bvf);
            }
        }
    }
}

// ---------------------------------------------------------------
// Output GEMM (f32 out), split-K + double-buffered stage-early (R12).
// ---------------------------------------------------------------
__global__ __launch_bounds__(512) void gemm_out_ks(
    const ushort_t* __restrict__ A, const ushort_t* __restrict__ W,
    const float* __restrict__ bias, float* __restrict__ C,
    int M, int N, int K)
{
    __shared__ __attribute__((aligned(16))) unsigned char smem[65536];
    float* red = (float*)smem;                 // used after K-loop

    const int tid  = threadIdx.x;
    const int lane = tid & 63;
    const int wave = tid >> 6;                 // 0..7
    const int g    = wave >> 2;                // k-half group
    const int q    = wave & 3;                 // quadrant
    const int wm   = q >> 1, wn = q & 1;
    const int nbn  = N >> 7;

    int nwg = gridDim.x;
    int bid = blockIdx.x;
    int nb  = (nwg & 7) ? bid : ((bid & 7) * (nwg >> 3) + (bid >> 3));
    const int bm = nb / nbn;
    const int bn = nb % nbn;
    const int m0 = bm << 7, n0 = bn << 7;

    f32x4 acc[4][4] = {};

    const int frow = lane & 15;
    const int kg   = lane >> 4;

    const ushort_t* gA[2]; const ushort_t* gB[2];
    int eofs[2];
#pragma unroll
    for (int j = 0; j < 2; ++j) {
        int t = wave * 2 + j;
        int c = t * 64 + lane;
        int r = c >> 3, s = c & 7;
        int ksrc = s ^ (r & 7);
        gA[j] = A + (size_t)(m0 + r) * K + ksrc * 8;
        gB[j] = W + (size_t)(n0 + r) * K + ksrc * 8;
        eofs[j] = t * 512;
    }

    const int nt = K >> 6;
#pragma unroll
    for (int j = 0; j < 2; ++j) {
        gload_lds16(gA[j], (ushort_t*)smem + eofs[j]);
        gload_lds16(gB[j], (ushort_t*)(smem + 16384) + eofs[j]);
    }
    __syncthreads();

    for (int t = 0; t < nt; ++t) {
        const int cur = t & 1;
        if (t + 1 < nt) {
            const int nxt = cur ^ 1;
            const int ko = (t + 1) << 6;
#pragma unroll
            for (int j = 0; j < 2; ++j) {
                gload_lds16(gA[j] + ko, (ushort_t*)(smem + nxt * 32768) + eofs[j]);
                gload_lds16(gB[j] + ko, (ushort_t*)(smem + nxt * 32768 + 16384) + eofs[j]);
            }
        }
        const ushort_t* bufA = (const ushort_t*)(smem + cur * 32768);
        const ushort_t* bufB = (const ushort_t*)(smem + cur * 32768 + 16384);

        bf16x8 af[4], bfr[4];
#pragma unroll
        for (int mi = 0; mi < 4; ++mi) {
            int r = (wm << 6) + (mi << 4) + frow;
            int sl = ((g << 2) + kg) ^ (r & 7);
            af[mi] = *(const bf16x8*)(bufA + (r * 8 + sl) * 8);
        }
#pragma unroll
        for (int ni = 0; ni < 4; ++ni) {
            int r = (wn << 6) + (ni << 4) + frow;
            int sl = ((g << 2) + kg) ^ (r & 7);
            bfr[ni] = *(const bf16x8*)(bufB + (r * 8 + sl) * 8);
        }
#pragma unroll
        for (int mi = 0; mi < 4; ++mi)
#pragma unroll
            for (int ni = 0; ni < 4; ++ni)
                acc[mi][ni] = __builtin_amdgcn_mfma_f32_16x16x32_bf16(
                    af[mi], bfr[ni], acc[mi][ni], 0, 0, 0);

        __syncthreads();
    }

    if (g == 1) {
#pragma unroll
        for (int mi = 0; mi < 4; ++mi)
#pragma unroll
            for (int ni = 0; ni < 4; ++ni)
                *(f32x4*)(red + q * 4096 + (mi * 4 + ni) * 256 + lane * 4) =
                    acc[mi][ni];
    }
    __syncthreads();

    if (g == 0) {
        const int orow = (lane >> 4) << 2;
        const int ocol = lane & 15;
#pragma unroll
        for (int ni = 0; ni < 4; ++ni) {
            int col = n0 + (wn << 6) + (ni << 4) + ocol;
            float bvf = bias[col];
#pragma unroll
            for (int mi = 0; mi < 4; ++mi) {
                f32x4 other = *(const f32x4*)(red + q * 4096 + (mi * 4 + ni) * 256 + lane * 4);
#pragma unroll
                for (int r = 0; r < 4; ++r) {
                    int row = m0 + (wm << 6) + (mi << 4) + orow + r;
                    C[(size_t)row * N + col] = acc[mi][ni][r] + other[r] + bvf;
                }
            }
        }
    }
}

// ---------------------------------------------------------------
// MFMA windowed-causal GQA attention WITH fused RMSNorm+RoPE (R10/R15).
// ---------------------------------------------------------------
__global__ __launch_bounds__(256) void attn_mfma(
    const ushort_t* __restrict__ qkv, const float* __restrict__ qn_w,
    const float* __restrict__ kn_w, const float* __restrict__ scp,
    const float2* __restrict__ rtab, ushort_t* __restrict__ ao)
{
    __shared__ __attribute__((aligned(16))) ushort_t sK[16384];   // K tile, then P(f32)
    __shared__ __attribute__((aligned(16))) ushort_t sVT[16384];  // V^T tile

    const int tid  = threadIdx.x;
    const int lane = tid & 63;
    const int w    = tid >> 6;
    const int c    = lane & 15;
    const int g    = lane >> 4;

    const int blk = blockIdx.x;
    const int qt  = blk & 31;
    const int h   = (blk >> 5) & 15;
    const int b   = blk >> 9;
    const int kvh = h >> 2;
    const int i0  = qt << 6;
    const int jb  = i0 - 64;
    const float scale = scp[0];

    // ---- Q fragments: load raw, fused rmsnorm + rope + scale ----
    bf16x8 aq[4];
    {
        const int srow = i0 + w * 16 + c;                 // seq position
        const ushort_t* qp = qkv + ((size_t)(b * 2048 + srow)) * NQKV
                                 + h * 128 + g * 8;
        float xv[4][8];
        float ss = 0.f;
#pragma unroll
        for (int ks = 0; ks < 4; ++ks) {
            ushort_t raw[8];
            *(uint4*)raw = *(const uint4*)(qp + ks * 32);
#pragma unroll
            for (int j = 0; j < 8; ++j) {
                float xf = b2f(raw[j]);
                xv[ks][j] = xf;
                ss += xf * xf;
            }
        }
        ss += __shfl_xor(ss, 16, 64);
        ss += __shfl_xor(ss, 32, 64);
        float inv = rsqrtf(ss * (1.0f / 128.0f) + 1e-8f) * scale;
#pragma unroll
        for (int ks = 0; ks < 4; ++ks) {
            ushort_t outb[8];
#pragma unroll
            for (int jj = 0; jj < 4; ++jj) {
                int d = ks * 32 + g * 8 + 2 * jj;
                float2 w2 = *(const float2*)(qn_w + d);
                float x0 = xv[ks][2 * jj]     * inv * w2.x;
                float x1 = xv[ks][2 * jj + 1] * inv * w2.y;
                float2 cs = rtab[(srow << 6) + (d >> 1)];
                outb[2 * jj]     = f2b(x0 * cs.x - x1 * cs.y);
                outb[2 * jj + 1] = f2b(x0 * cs.y + x1 * cs.x);
            }
            aq[ks] = *(const bf16x8*)outb;
        }
    }

    // ---- stage K rows [key][d] with fused rmsnorm + rope ----
    const ushort_t* kvb = qkv + ((size_t)b * 2048) * NQKV + 2048 + kvh * 128;
#pragma unroll
    for (int it = 0; it < 8; ++it) {
        int idx = it * 256 + tid;
        int rr = idx >> 4, cc = idx & 15;
        int j = jb + rr; if (j < 0) j = 0;
        ushort_t raw[8];
        *(uint4*)raw = *(const uint4*)(kvb + (size_t)j * NQKV + cc * 8);
        float xv[8];
        float ss = 0.f;
#pragma unroll
        for (int jj = 0; jj < 8; ++jj) {
            xv[jj] = b2f(raw[jj]);
            ss += xv[jj] * xv[jj];
        }
        ss += __shfl_xor(ss, 1, 64);
        ss += __shfl_xor(ss, 2, 64);
        ss += __shfl_xor(ss, 4, 64);
        ss += __shfl_xor(ss, 8, 64);
        float inv = rsqrtf(ss * (1.0f / 128.0f) + 1e-8f);
        ushort_t outb[8];
#pragma unroll
        for (int jj = 0; jj < 4; ++jj) {
            int d = cc * 8 + 2 * jj;
            float2 w2 = *(const float2*)(kn_w + d);
            float x0 = xv[2 * jj]     * inv * w2.x;
            float x1 = xv[2 * jj + 1] * inv * w2.y;
            float2 cs = rtab[(j << 6) + (d >> 1)];
            outb[2 * jj]     = f2b(x0 * cs.x - x1 * cs.y);
            outb[2 * jj + 1] = f2b(x0 * cs.y + x1 * cs.x);
        }
        int f2v = (rr & 15) ^ ((rr >> 3) & 15);
        *(uint4*)(sK + (rr * 16 + (cc ^ f2v)) * 8) = *(const uint4*)outb;
    }
    // ---- stage V transposed: VT[d][key] (no norm) ----
#pragma unroll
    for (int it = 0; it < 4; ++it) {
        int task = it * 256 + tid;
        int pp = task >> 4, d8 = task & 15;
        int j0 = jb + 2 * pp;     if (j0 < 0) j0 = 0;
        int j1 = jb + 2 * pp + 1; if (j1 < 0) j1 = 0;
        ushort_t e0[8]; *(uint4*)e0 = *(const uint4*)(kvb + (size_t)j0 * NQKV + 512 + d8 * 8);
        ushort_t e1[8]; *(uint4*)e1 = *(const uint4*)(kvb + (size_t)j1 * NQKV + 512 + d8 * 8);
        int cc = pp >> 2;
#pragma unroll
        for (int jj = 0; jj < 8; ++jj) {
            int rr = d8 * 8 + jj;
            int f2v = (rr & 15) ^ ((rr >> 3) & 15);
            unsigned int word = (unsigned int)e0[jj] | ((unsigned int)e1[jj] << 16);
            *(unsigned int*)(sVT + (rr * 16 + (cc ^ f2v)) * 8 + (pp & 3) * 2) = word;
        }
    }
    __syncthreads();

    // ---- S = Q K^T (scale pre-folded into Q) ----
    f32x4 s[8] = {};
    __builtin_amdgcn_s_setprio(1);
#pragma unroll
    for (int nt = 0; nt < 8; ++nt) {
        int rr = nt * 16 + c;
        int f2v = (rr & 15) ^ ((rr >> 3) & 15);
#pragma unroll
        for (int ks = 0; ks < 4; ++ks) {
            bf16x8 bk = *(const bf16x8*)(sK + (rr * 16 + ((ks * 4 + g) ^ f2v)) * 8);
            s[nt] = __builtin_amdgcn_mfma_f32_16x16x32_bf16(aq[ks], bk, s[nt], 0, 0, 0);
        }
    }
    __builtin_amdgcn_s_setprio(0);

    // ---- mask + row softmax ----
    float linv[4];
#pragma unroll
    for (int r = 0; r < 4; ++r) {
        int qb = w * 16 + g * 4 + r;
#pragma unroll
        for (int nt = 0; nt < 8; ++nt) {
            int jl = nt * 16 + c;
            bool valid = (jl >= qb) && (jl <= qb + 64) && (i0 + jl >= 64);
            s[nt][r] = valid ? s[nt][r] : -1e30f;
        }
        float m = s[0][r];
#pragma unroll
        for (int nt = 1; nt < 8; ++nt) m = fmaxf(m, s[nt][r]);
#pragma unroll
        for (int off = 1; off <= 8; off <<= 1) m = fmaxf(m, __shfl_xor(m, off, 64));
        float sum = 0.f;
#pragma unroll
        for (int nt = 0; nt < 8; ++nt) {
            float e = __expf(s[nt][r] - m);
            s[nt][r] = e;
            sum += e;
        }
#pragma unroll
        for (int off = 1; off <= 8; off <<= 1) sum += __shfl_xor(sum, off, 64);
        linv[r] = 1.0f / sum;
    }

    // ---- P via LDS ----
    __syncthreads();
    float* Pw = (float*)sK + w * 2048;
#pragma unroll
    for (int nt = 0; nt < 8; ++nt) {
#pragma unroll
        for (int r = 0; r < 4; ++r) {
            int q = g * 4 + r;
            int chunk = nt * 4 + (c >> 2);
            Pw[q * 128 + ((chunk ^ (q & 7)) * 4) + (c & 3)] = s[nt][r];
        }
    }

    // ---- O = P V ----
    f32x4 o[8] = {};
#pragma unroll
    for (int kt = 0; kt < 4; ++kt) {
        float pf[8];
#pragma unroll
        for (int e = 0; e < 2; ++e) {
            int chunk = kt * 8 + g * 2 + e;
            f32x4 v4 = *(const f32x4*)(Pw + c * 128 + ((chunk ^ (c & 7)) * 4));
            pf[e * 4 + 0] = v4[0]; pf[e * 4 + 1] = v4[1];
            pf[e * 4 + 2] = v4[2]; pf[e * 4 + 3] = v4[3];
        }
        ushort_t pb[8];
#pragma unroll
        for (int j = 0; j < 8; ++j) pb[j] = f2b(pf[j]);
        bf16x8 pa = *(const bf16x8*)pb;
        __builtin_amdgcn_s_setprio(1);
#pragma unroll
        for (int dt = 0; dt < 8; ++dt) {
            int rr = dt * 16 + c;
            int f2v = (rr & 15) ^ ((rr >> 3) & 15);
            bf16x8 bv = *(const bf16x8*)(sVT + (rr * 16 + ((kt * 4 + g) ^ f2v)) * 8);
            o[dt] = __builtin_amdgcn_mfma_f32_16x16x32_bf16(pa, bv, o[dt], 0, 0, 0);
        }
        __builtin_amdgcn_s_setprio(0);
    }

    // ---- epilogue ----
    const size_t orow0 = (size_t)(b * 2048 + i0 + w * 16);
#pragma unroll
    for (int dt = 0; dt < 8; ++dt) {
#pragma unroll
        for (int r = 0; r < 4; ++r) {
            int q = g * 4 + r;
            ao[(orow0 + q) * 2048 + h * 128 + dt * 16 + c] = f2b(o[dt][r] * linv[r]);
        }
    }
}

// ---------------------------------------------------------------
extern "C" void kernel_launch(void* const* d_in, const int* in_sizes, int n_in,
                              void* d_out, int out_size, void* d_ws, size_t ws_size,
                              hipStream_t stream)
{
    const float* x   = (const float*)d_in[0];
    const float* Wq  = (const float*)d_in[1];
    const float* bq  = (const float*)d_in[2];
    const float* Wk  = (const float*)d_in[3];
    const float* bk  = (const float*)d_in[4];
    const float* Wv  = (const float*)d_in[5];
    const float* bv  = (const float*)d_in[6];
    const float* Wo  = (const float*)d_in[7];
    const float* bo  = (const float*)d_in[8];
    const float* qnw = (const float*)d_in[9];
    const float* knw = (const float*)d_in[10];
    const float* scp = (const float*)d_in[11];
    float* out = (float*)d_out;

    const int M = BATCH * SEQ;             // 4096
    ushort_t* xb    = (ushort_t*)d_ws;                      // M x 2048 (later: ao)
    ushort_t* qkv0  = xb   + (size_t)M * DMODEL;            // M x 3072 (raw)
    ushort_t* Wqkvb = qkv0 + (size_t)M * NQKV;              // 3072 x 2048
    ushort_t* Wob   = Wqkvb + (size_t)NQKV * DMODEL;        // 2048 x 2048
    float*    bqkv  = (float*)(Wob + (size_t)DMODEL * DMODEL); // 3072 f32
    float2*   rtab  = (float2*)(bqkv + 3072);               // 2048*64 float2 (1MB)
    ushort_t* ao    = xb;
    (void)ws_size; (void)in_sizes; (void)n_in; (void)out_size;

    // allow 128KB dynamic LDS for the 8-phase GEMM (host-side, idempotent)
    hipFuncSetAttribute((const void*)gemm_qkv_8p,
                        hipFuncAttributeMaxDynamicSharedMemorySize, 131072);

    prep<<<dim3(9740), 256, 0, stream>>>(x, Wq, Wk, Wv, Wo, bq, bk, bv,
                                         xb, Wqkvb, bqkv, rtab);
    gemm_qkv_8p<<<dim3((M / 256) * (NQKV / 256)), 512, 131072, stream>>>(
        xb, Wqkvb, bqkv, qkv0, M, NQKV, DMODEL);
    attn_mfma<<<dim3(BATCH * NHEADS * (SEQ / 64)), 256, 0, stream>>>(
        qkv0, qnw, knw, scp, rtab, ao);
    gemm_out_ks<<<dim3((M / 128) * (DMODEL / 128)), 512, 0, stream>>>(
        ao, Wob, bo, out, M, DMODEL, DMODEL);
}

// Round 18
// 138.301 us; speedup vs baseline: 1.0735x; 1.0735x over previous
//
#include <hip/hip_runtime.h>

// ---------------- problem constants ----------------
#define BATCH 2
#define SEQ 2048
#define DMODEL 2048
#define NHEADS 16
#define NKV 4
#define DK 128
#define WINH 64   // WINDOW/2
#define NQKV 3072 // 2048 q + 512 k + 512 v

typedef unsigned short ushort_t;
typedef __attribute__((ext_vector_type(8))) __bf16 bf16x8;
typedef __attribute__((ext_vector_type(4))) float f32x4;

__device__ __forceinline__ float b2f(ushort_t u) {
    union { unsigned int i; float f; } v; v.i = ((unsigned int)u) << 16; return v.f;
}
__device__ __forceinline__ ushort_t f2b(float f) {
    union { float f; unsigned int i; } v; v.f = f;
    unsigned int r = v.i + 0x7FFFu + ((v.i >> 16) & 1u);
    return (ushort_t)(r >> 16);
}

// async global->LDS, 16B/lane; LDS dest wave-uniform base + lane*16.
__device__ __forceinline__ void gload_lds16(const ushort_t* g, ushort_t* l) {
    __builtin_amdgcn_global_load_lds(
        (__attribute__((address_space(1))) void*)(void*)const_cast<ushort_t*>(g),
        (__attribute__((address_space(3))) void*)l, 16, 0, 0);
}

// ---------------------------------------------------------------
// prep: all input conversion in ONE launch (blockIdx ranges).
// ~113 MB moved -> ~17us, at HBM roofline.
// ---------------------------------------------------------------
__global__ __launch_bounds__(256) void prep(
    const float* __restrict__ x,  const float* __restrict__ Wq,
    const float* __restrict__ Wk, const float* __restrict__ Wv,
    const float* __restrict__ Wo, const float* __restrict__ bq,
    const float* __restrict__ bk, const float* __restrict__ bv,
    ushort_t* __restrict__ xb, ushort_t* __restrict__ wdst,
    float* __restrict__ bqkv, float2* __restrict__ rtab)
{
    const int blk = blockIdx.x;
    const int tid = threadIdx.x;
    if (blk < 4096) {                               // x cast
        int i = blk * 256 + tid;
        float4 a = *((const float4*)x + i * 2);
        float4 b = *((const float4*)x + i * 2 + 1);
        ushort_t o[8] = { f2b(a.x), f2b(a.y), f2b(a.z), f2b(a.w),
                          f2b(b.x), f2b(b.y), f2b(b.z), f2b(b.w) };
        *((uint4*)xb + i) = *(const uint4*)o;
    } else if (blk < 9216) {                        // weights cast
        int i = (blk - 4096) * 256 + tid;
        int row = i >> 8, c8 = i & 255;
        const float* src;
        if      (row < 2048) src = Wq + (size_t)row * 2048;
        else if (row < 2560) src = Wk + (size_t)(row - 2048) * 2048;
        else if (row < 3072) src = Wv + (size_t)(row - 2560) * 2048;
        else                 src = Wo + (size_t)(row - 3072) * 2048;
        float4 a = *((const float4*)src + c8 * 2);
        float4 b = *((const float4*)src + c8 * 2 + 1);
        ushort_t o[8] = { f2b(a.x), f2b(a.y), f2b(a.z), f2b(a.w),
                          f2b(b.x), f2b(b.y), f2b(b.z), f2b(b.w) };
        *((uint4*)wdst + i) = *(const uint4*)o;
    } else if (blk < 9228) {                        // bias concat
        int i = (blk - 9216) * 256 + tid;
        if (i < 2048) bqkv[i] = bq[i];
        else if (i < 2560) bqkv[i] = bk[i - 2048];
        else if (i < 3072) bqkv[i] = bv[i - 2560];
    } else {                                        // rope table
        int i = (blk - 9228) * 256 + tid;           // 0..131071
        int s = i >> 6, dd = i & 63;
        float invfreq = exp2f(-(float)(2 * dd) * (13.287712379549449f / 128.0f));
        float ang = (float)s * invfreq;
        rtab[i] = make_float2(cosf(ang), sinf(ang));
    }
}

// ---------------------------------------------------------------
// QKV GEMM — FINAL (verified 56.0-56.5us / ~910 TF): 128x128 tile,
// BK=64, 4 waves 2x2, global_load_lds w16, slot s^(r&7) swizzle (0 conf),
// 2-barrier K-loop, 3 blocks/CU. Four deeper-pipeline variants (R11 256²
// dbuf, R13 256x192 counted-vmcnt, R14 quad-buf depth-3, R16 8-phase)
// all measured SLOWER (63.8/59.0/71.5/74.5): cross-block TLP at 3 blk/CU
// is the winning latency-hiding mechanism for this shape.
// Bijective XCD swizzle (grid 768 % 8 == 0).
// ---------------------------------------------------------------
__global__ __launch_bounds__(256) void gemm_qkv(
    const ushort_t* __restrict__ A, const ushort_t* __restrict__ W,
    const float* __restrict__ bias, ushort_t* __restrict__ C,
    int M, int N, int K)
{
    __shared__ __attribute__((aligned(16))) ushort_t sA[8192];
    __shared__ __attribute__((aligned(16))) ushort_t sB[8192];

    const int tid  = threadIdx.x;
    const int lane = tid & 63;
    const int wave = tid >> 6;
    const int nbn  = N >> 7;

    int nwg = gridDim.x;
    int bid = blockIdx.x;
    int nb  = (nwg & 7) ? bid : ((bid & 7) * (nwg >> 3) + (bid >> 3));
    const int bm = nb / nbn;
    const int bn = nb % nbn;
    const int m0 = bm << 7, n0 = bn << 7;
    const int wm = wave >> 1, wn = wave & 1;

    f32x4 acc[4][4] = {};

    const int frow = lane & 15;
    const int kg   = lane >> 4;

    const ushort_t* gA[4]; const ushort_t* gB[4];
    ushort_t* lA[4]; ushort_t* lB[4];
#pragma unroll
    for (int j = 0; j < 4; ++j) {
        int t = wave * 4 + j;
        int c = t * 64 + lane;
        int r = c >> 3, s = c & 7;
        int ksrc = s ^ (r & 7);
        gA[j] = A + (size_t)(m0 + r) * K + ksrc * 8;
        gB[j] = W + (size_t)(n0 + r) * K + ksrc * 8;
        lA[j] = sA + t * 512;
        lB[j] = sB + t * 512;
    }

    for (int k0 = 0; k0 < K; k0 += 64) {
        if (k0) __syncthreads();
#pragma unroll
        for (int j = 0; j < 4; ++j) gload_lds16(gA[j] + k0, lA[j]);
#pragma unroll
        for (int j = 0; j < 4; ++j) gload_lds16(gB[j] + k0, lB[j]);
        __syncthreads();

        bf16x8 af[4][2], bfr[4][2];
#pragma unroll
        for (int mi = 0; mi < 4; ++mi)
#pragma unroll
            for (int kk = 0; kk < 2; ++kk) {
                int r = (wm << 6) + (mi << 4) + frow;
                int sl = (kk * 4 + kg) ^ (r & 7);
                af[mi][kk] = *(const bf16x8*)(sA + (r * 8 + sl) * 8);
            }
#pragma unroll
        for (int ni = 0; ni < 4; ++ni)
#pragma unroll
            for (int kk = 0; kk < 2; ++kk) {
                int r = (wn << 6) + (ni << 4) + frow;
                int sl = (kk * 4 + kg) ^ (r & 7);
                bfr[ni][kk] = *(const bf16x8*)(sB + (r * 8 + sl) * 8);
            }
#pragma unroll
        for (int kk = 0; kk < 2; ++kk)
#pragma unroll
            for (int mi = 0; mi < 4; ++mi)
#pragma unroll
                for (int ni = 0; ni < 4; ++ni)
                    acc[mi][ni] = __builtin_amdgcn_mfma_f32_16x16x32_bf16(
                        af[mi][kk], bfr[ni][kk], acc[mi][ni], 0, 0, 0);
    }

    // D: col = lane&15, row = (lane>>4)*4 + reg  [m89-verified]
    const int orow = (lane >> 4) << 2;
    const int ocol = lane & 15;
#pragma unroll
    for (int ni = 0; ni < 4; ++ni) {
        int col = n0 + (wn << 6) + (ni << 4) + ocol;
        float bvf = bias[col];
#pragma unroll
        for (int mi = 0; mi < 4; ++mi) {
#pragma unroll
            for (int r = 0; r < 4; ++r) {
                int row = m0 + (wm << 6) + (mi << 4) + orow + r;
                C[(size_t)row * N + col] = f2b(acc[mi][ni][r] + bvf);
            }
        }
    }
}

// ---------------------------------------------------------------
// Output GEMM (f32 out), split-K + double-buffered stage-early (R12,
// best-measured for this dispatch: < 56us, out of top-5 since R12).
// ---------------------------------------------------------------
__global__ __launch_bounds__(512) void gemm_out_ks(
    const ushort_t* __restrict__ A, const ushort_t* __restrict__ W,
    const float* __restrict__ bias, float* __restrict__ C,
    int M, int N, int K)
{
    __shared__ __attribute__((aligned(16))) unsigned char smem[65536];
    float* red = (float*)smem;                 // used after K-loop

    const int tid  = threadIdx.x;
    const int lane = tid & 63;
    const int wave = tid >> 6;                 // 0..7
    const int g    = wave >> 2;                // k-half group
    const int q    = wave & 3;                 // quadrant
    const int wm   = q >> 1, wn = q & 1;
    const int nbn  = N >> 7;

    int nwg = gridDim.x;
    int bid = blockIdx.x;
    int nb  = (nwg & 7) ? bid : ((bid & 7) * (nwg >> 3) + (bid >> 3));
    const int bm = nb / nbn;
    const int bn = nb % nbn;
    const int m0 = bm << 7, n0 = bn << 7;

    f32x4 acc[4][4] = {};

    const int frow = lane & 15;
    const int kg   = lane >> 4;

    const ushort_t* gA[2]; const ushort_t* gB[2];
    int eofs[2];
#pragma unroll
    for (int j = 0; j < 2; ++j) {
        int t = wave * 2 + j;
        int c = t * 64 + lane;
        int r = c >> 3, s = c & 7;
        int ksrc = s ^ (r & 7);
        gA[j] = A + (size_t)(m0 + r) * K + ksrc * 8;
        gB[j] = W + (size_t)(n0 + r) * K + ksrc * 8;
        eofs[j] = t * 512;
    }

    const int nt = K >> 6;
#pragma unroll
    for (int j = 0; j < 2; ++j) {
        gload_lds16(gA[j], (ushort_t*)smem + eofs[j]);
        gload_lds16(gB[j], (ushort_t*)(smem + 16384) + eofs[j]);
    }
    __syncthreads();

    for (int t = 0; t < nt; ++t) {
        const int cur = t & 1;
        if (t + 1 < nt) {
            const int nxt = cur ^ 1;
            const int ko = (t + 1) << 6;
#pragma unroll
            for (int j = 0; j < 2; ++j) {
                gload_lds16(gA[j] + ko, (ushort_t*)(smem + nxt * 32768) + eofs[j]);
                gload_lds16(gB[j] + ko, (ushort_t*)(smem + nxt * 32768 + 16384) + eofs[j]);
            }
        }
        const ushort_t* bufA = (const ushort_t*)(smem + cur * 32768);
        const ushort_t* bufB = (const ushort_t*)(smem + cur * 32768 + 16384);

        bf16x8 af[4], bfr[4];
#pragma unroll
        for (int mi = 0; mi < 4; ++mi) {
            int r = (wm << 6) + (mi << 4) + frow;
            int sl = ((g << 2) + kg) ^ (r & 7);
            af[mi] = *(const bf16x8*)(bufA + (r * 8 + sl) * 8);
        }
#pragma unroll
        for (int ni = 0; ni < 4; ++ni) {
            int r = (wn << 6) + (ni << 4) + frow;
            int sl = ((g << 2) + kg) ^ (r & 7);
            bfr[ni] = *(const bf16x8*)(bufB + (r * 8 + sl) * 8);
        }
#pragma unroll
        for (int mi = 0; mi < 4; ++mi)
#pragma unroll
            for (int ni = 0; ni < 4; ++ni)
                acc[mi][ni] = __builtin_amdgcn_mfma_f32_16x16x32_bf16(
                    af[mi], bfr[ni], acc[mi][ni], 0, 0, 0);

        __syncthreads();
    }

    if (g == 1) {
#pragma unroll
        for (int mi = 0; mi < 4; ++mi)
#pragma unroll
            for (int ni = 0; ni < 4; ++ni)
                *(f32x4*)(red + q * 4096 + (mi * 4 + ni) * 256 + lane * 4) =
                    acc[mi][ni];
    }
    __syncthreads();

    if (g == 0) {
        const int orow = (lane >> 4) << 2;
        const int ocol = lane & 15;
#pragma unroll
        for (int ni = 0; ni < 4; ++ni) {
            int col = n0 + (wn << 6) + (ni << 4) + ocol;
            float bvf = bias[col];
#pragma unroll
            for (int mi = 0; mi < 4; ++mi) {
                f32x4 other = *(const f32x4*)(red + q * 4096 + (mi * 4 + ni) * 256 + lane * 4);
#pragma unroll
                for (int r = 0; r < 4; ++r) {
                    int row = m0 + (wm << 6) + (mi << 4) + orow + r;
                    C[(size_t)row * N + col] = acc[mi][ni][r] + other[r] + bvf;
                }
            }
        }
    }
}

// ---------------------------------------------------------------
// MFMA windowed-causal GQA attention WITH fused RMSNorm+RoPE (R10).
// 64 queries/block, window union = 128 keys; exp(-1e30)==0 matches
// the reference's -10000 fill exactly in f32 softmax.
// ---------------------------------------------------------------
__global__ __launch_bounds__(256) void attn_mfma(
    const ushort_t* __restrict__ qkv, const float* __restrict__ qn_w,
    const float* __restrict__ kn_w, const float* __restrict__ scp,
    const float2* __restrict__ rtab, ushort_t* __restrict__ ao)
{
    __shared__ __attribute__((aligned(16))) ushort_t sK[16384];   // K tile, then P(f32)
    __shared__ __attribute__((aligned(16))) ushort_t sVT[16384];  // V^T tile

    const int tid  = threadIdx.x;
    const int lane = tid & 63;
    const int w    = tid >> 6;
    const int c    = lane & 15;
    const int g    = lane >> 4;

    const int blk = blockIdx.x;
    const int qt  = blk & 31;
    const int h   = (blk >> 5) & 15;
    const int b   = blk >> 9;
    const int kvh = h >> 2;
    const int i0  = qt << 6;
    const int jb  = i0 - 64;
    const float scale = scp[0];

    // ---- Q fragments: load raw, fused rmsnorm + rope + scale ----
    bf16x8 aq[4];
    {
        const int srow = i0 + w * 16 + c;                 // seq position
        const ushort_t* qp = qkv + ((size_t)(b * 2048 + srow)) * NQKV
                                 + h * 128 + g * 8;
        float xv[4][8];
        float ss = 0.f;
#pragma unroll
        for (int ks = 0; ks < 4; ++ks) {
            ushort_t raw[8];
            *(uint4*)raw = *(const uint4*)(qp + ks * 32);
#pragma unroll
            for (int j = 0; j < 8; ++j) {
                float xf = b2f(raw[j]);
                xv[ks][j] = xf;
                ss += xf * xf;
            }
        }
        ss += __shfl_xor(ss, 16, 64);
        ss += __shfl_xor(ss, 32, 64);
        float inv = rsqrtf(ss * (1.0f / 128.0f) + 1e-8f) * scale;
#pragma unroll
        for (int ks = 0; ks < 4; ++ks) {
            ushort_t outb[8];
#pragma unroll
            for (int jj = 0; jj < 4; ++jj) {
                int d = ks * 32 + g * 8 + 2 * jj;
                float2 w2 = *(const float2*)(qn_w + d);
                float x0 = xv[ks][2 * jj]     * inv * w2.x;
                float x1 = xv[ks][2 * jj + 1] * inv * w2.y;
                float2 cs = rtab[(srow << 6) + (d >> 1)];
                outb[2 * jj]     = f2b(x0 * cs.x - x1 * cs.y);
                outb[2 * jj + 1] = f2b(x0 * cs.y + x1 * cs.x);
            }
            aq[ks] = *(const bf16x8*)outb;
        }
    }

    // ---- stage K rows [key][d] with fused rmsnorm + rope ----
    const ushort_t* kvb = qkv + ((size_t)b * 2048) * NQKV + 2048 + kvh * 128;
#pragma unroll
    for (int it = 0; it < 8; ++it) {
        int idx = it * 256 + tid;
        int rr = idx >> 4, cc = idx & 15;
        int j = jb + rr; if (j < 0) j = 0;
        ushort_t raw[8];
        *(uint4*)raw = *(const uint4*)(kvb + (size_t)j * NQKV + cc * 8);
        float xv[8];
        float ss = 0.f;
#pragma unroll
        for (int jj = 0; jj < 8; ++jj) {
            xv[jj] = b2f(raw[jj]);
            ss += xv[jj] * xv[jj];
        }
        ss += __shfl_xor(ss, 1, 64);
        ss += __shfl_xor(ss, 2, 64);
        ss += __shfl_xor(ss, 4, 64);
        ss += __shfl_xor(ss, 8, 64);
        float inv = rsqrtf(ss * (1.0f / 128.0f) + 1e-8f);
        ushort_t outb[8];
#pragma unroll
        for (int jj = 0; jj < 4; ++jj) {
            int d = cc * 8 + 2 * jj;
            float2 w2 = *(const float2*)(kn_w + d);
            float x0 = xv[2 * jj]     * inv * w2.x;
            float x1 = xv[2 * jj + 1] * inv * w2.y;
            float2 cs = rtab[(j << 6) + (d >> 1)];
            outb[2 * jj]     = f2b(x0 * cs.x - x1 * cs.y);
            outb[2 * jj + 1] = f2b(x0 * cs.y + x1 * cs.x);
        }
        int f2v = (rr & 15) ^ ((rr >> 3) & 15);
        *(uint4*)(sK + (rr * 16 + (cc ^ f2v)) * 8) = *(const uint4*)outb;
    }
    // ---- stage V transposed: VT[d][key] (no norm) ----
#pragma unroll
    for (int it = 0; it < 4; ++it) {
        int task = it * 256 + tid;
        int pp = task >> 4, d8 = task & 15;
        int j0 = jb + 2 * pp;     if (j0 < 0) j0 = 0;
        int j1 = jb + 2 * pp + 1; if (j1 < 0) j1 = 0;
        ushort_t e0[8]; *(uint4*)e0 = *(const uint4*)(kvb + (size_t)j0 * NQKV + 512 + d8 * 8);
        ushort_t e1[8]; *(uint4*)e1 = *(const uint4*)(kvb + (size_t)j1 * NQKV + 512 + d8 * 8);
        int cc = pp >> 2;
#pragma unroll
        for (int jj = 0; jj < 8; ++jj) {
            int rr = d8 * 8 + jj;
            int f2v = (rr & 15) ^ ((rr >> 3) & 15);
            unsigned int word = (unsigned int)e0[jj] | ((unsigned int)e1[jj] << 16);
            *(unsigned int*)(sVT + (rr * 16 + (cc ^ f2v)) * 8 + (pp & 3) * 2) = word;
        }
    }
    __syncthreads();

    // ---- S = Q K^T (scale pre-folded into Q) ----
    f32x4 s[8] = {};
#pragma unroll
    for (int nt = 0; nt < 8; ++nt) {
        int rr = nt * 16 + c;
        int f2v = (rr & 15) ^ ((rr >> 3) & 15);
#pragma unroll
        for (int ks = 0; ks < 4; ++ks) {
            bf16x8 bk = *(const bf16x8*)(sK + (rr * 16 + ((ks * 4 + g) ^ f2v)) * 8);
            s[nt] = __builtin_amdgcn_mfma_f32_16x16x32_bf16(aq[ks], bk, s[nt], 0, 0, 0);
        }
    }

    // ---- mask + row softmax ----
    float linv[4];
#pragma unroll
    for (int r = 0; r < 4; ++r) {
        int qb = w * 16 + g * 4 + r;
#pragma unroll
        for (int nt = 0; nt < 8; ++nt) {
            int jl = nt * 16 + c;
            bool valid = (jl >= qb) && (jl <= qb + 64) && (i0 + jl >= 64);
            s[nt][r] = valid ? s[nt][r] : -1e30f;
        }
        float m = s[0][r];
#pragma unroll
        for (int nt = 1; nt < 8; ++nt) m = fmaxf(m, s[nt][r]);
#pragma unroll
        for (int off = 1; off <= 8; off <<= 1) m = fmaxf(m, __shfl_xor(m, off, 64));
        float sum = 0.f;
#pragma unroll
        for (int nt = 0; nt < 8; ++nt) {
            float e = __expf(s[nt][r] - m);
            s[nt][r] = e;
            sum += e;
        }
#pragma unroll
        for (int off = 1; off <= 8; off <<= 1) sum += __shfl_xor(sum, off, 64);
        linv[r] = 1.0f / sum;
    }

    // ---- P via LDS ----
    __syncthreads();
    float* Pw = (float*)sK + w * 2048;
#pragma unroll
    for (int nt = 0; nt < 8; ++nt) {
#pragma unroll
        for (int r = 0; r < 4; ++r) {
            int q = g * 4 + r;
            int chunk = nt * 4 + (c >> 2);
            Pw[q * 128 + ((chunk ^ (q & 7)) * 4) + (c & 3)] = s[nt][r];
        }
    }

    // ---- O = P V ----
    f32x4 o[8] = {};
#pragma unroll
    for (int kt = 0; kt < 4; ++kt) {
        float pf[8];
#pragma unroll
        for (int e = 0; e < 2; ++e) {
            int chunk = kt * 8 + g * 2 + e;
            f32x4 v4 = *(const f32x4*)(Pw + c * 128 + ((chunk ^ (c & 7)) * 4));
            pf[e * 4 + 0] = v4[0]; pf[e * 4 + 1] = v4[1];
            pf[e * 4 + 2] = v4[2]; pf[e * 4 + 3] = v4[3];
        }
        ushort_t pb[8];
#pragma unroll
        for (int j = 0; j < 8; ++j) pb[j] = f2b(pf[j]);
        bf16x8 pa = *(const bf16x8*)pb;
#pragma unroll
        for (int dt = 0; dt < 8; ++dt) {
            int rr = dt * 16 + c;
            int f2v = (rr & 15) ^ ((rr >> 3) & 15);
            bf16x8 bv = *(const bf16x8*)(sVT + (rr * 16 + ((kt * 4 + g) ^ f2v)) * 8);
            o[dt] = __builtin_amdgcn_mfma_f32_16x16x32_bf16(pa, bv, o[dt], 0, 0, 0);
        }
    }

    // ---- epilogue ----
    const size_t orow0 = (size_t)(b * 2048 + i0 + w * 16);
#pragma unroll
    for (int dt = 0; dt < 8; ++dt) {
#pragma unroll
        for (int r = 0; r < 4; ++r) {
            int q = g * 4 + r;
            ao[(orow0 + q) * 2048 + h * 128 + dt * 16 + c] = f2b(o[dt][r] * linv[r]);
        }
    }
}

// ---------------------------------------------------------------
extern "C" void kernel_launch(void* const* d_in, const int* in_sizes, int n_in,
                              void* d_out, int out_size, void* d_ws, size_t ws_size,
                              hipStream_t stream)
{
    const float* x   = (const float*)d_in[0];
    const float* Wq  = (const float*)d_in[1];
    const float* bq  = (const float*)d_in[2];
    const float* Wk  = (const float*)d_in[3];
    const float* bk  = (const float*)d_in[4];
    const float* Wv  = (const float*)d_in[5];
    const float* bv  = (const float*)d_in[6];
    const float* Wo  = (const float*)d_in[7];
    const float* bo  = (const float*)d_in[8];
    const float* qnw = (const float*)d_in[9];
    const float* knw = (const float*)d_in[10];
    const float* scp = (const float*)d_in[11];
    float* out = (float*)d_out;

    const int M = BATCH * SEQ;             // 4096
    ushort_t* xb    = (ushort_t*)d_ws;                      // M x 2048 (later: ao)
    ushort_t* qkv0  = xb   + (size_t)M * DMODEL;            // M x 3072 (raw)
    ushort_t* Wqkvb = qkv0 + (size_t)M * NQKV;              // 3072 x 2048
    ushort_t* Wob   = Wqkvb + (size_t)NQKV * DMODEL;        // 2048 x 2048
    float*    bqkv  = (float*)(Wob + (size_t)DMODEL * DMODEL); // 3072 f32
    float2*   rtab  = (float2*)(bqkv + 3072);               // 2048*64 float2 (1MB)
    ushort_t* ao    = xb;
    (void)ws_size; (void)in_sizes; (void)n_in; (void)out_size;

    prep<<<dim3(9740), 256, 0, stream>>>(x, Wq, Wk, Wv, Wo, bq, bk, bv,
                                         xb, Wqkvb, bqkv, rtab);
    gemm_qkv<<<dim3((M / 128) * (NQKV / 128)), 256, 0, stream>>>(
        xb, Wqkvb, bqkv, qkv0, M, NQKV, DMODEL);
    attn_mfma<<<dim3(BATCH * NHEADS * (SEQ / 64)), 256, 0, stream>>>(
        qkv0, qnw, knw, scp, rtab, ao);
    gemm_out_ks<<<dim3((M / 128) * (DMODEL / 128)), 512, 0, stream>>>(
        ao, Wob, bo, out, M, DMODEL, DMODEL);
}